// Round 12
// baseline (267.968 us; speedup 1.0000x reference)
//
#include <hip/hip_runtime.h>
#include <math.h>

#define NN 8192
#define KDIM 512
#define DD 256
#define NCB 256    // value buckets

typedef float4 f4;
typedef __attribute__((ext_vector_type(4))) float f4v;  // native vec for nontemporal

__device__ __forceinline__ float dot4(const f4& x, const f4& y) {
  return x.x * y.x + x.y * y.y + x.z * y.z + x.w * y.w;
}

// Monotone bucket map (exact float semantics: sub, mul by >=0, floor, clamp
// are all monotone) -> prefix sets factor exactly across buckets.
__device__ __forceinline__ int bk(float x, float tmin, float sc) {
  int b = (int)floorf((x - tmin) * sc);
  return b < 0 ? 0 : (b > NCB - 1 ? NCB - 1 : b);
}

// ---------- K1: H = X @ W (f32 vector GEMM, 64x64 tile) + s,t tail ----------
__global__ __launch_bounds__(256) void k_gemm(const float* __restrict__ X,
                                              const float* __restrict__ W,
                                              const float* __restrict__ av,
                                              float* __restrict__ H,
                                              float* __restrict__ s,
                                              float* __restrict__ t) {
  __shared__ float Xs[32][64];  // [k][r] (transposed); reused as wv1/wv2 after
  __shared__ float Ws[32][64];  // [k][c]
  const int tid = threadIdx.x;
  const int tx = tid & 15;
  const int ty = tid >> 4;
  const int r0 = blockIdx.x * 64;
  const int c0 = blockIdx.y * 64;
  float acc[4][4] = {};
  for (int k0 = 0; k0 < KDIM; k0 += 32) {
#pragma unroll
    for (int q = 0; q < 2; ++q) {
      int fi = tid + q * 256;
      int r = fi >> 3;
      int kq = fi & 7;
      f4 v = *reinterpret_cast<const f4*>(&X[(size_t)(r0 + r) * KDIM + k0 + kq * 4]);
      Xs[kq * 4 + 0][r] = v.x; Xs[kq * 4 + 1][r] = v.y;
      Xs[kq * 4 + 2][r] = v.z; Xs[kq * 4 + 3][r] = v.w;
    }
#pragma unroll
    for (int q = 0; q < 2; ++q) {
      int fi = tid + q * 256;
      int k = fi >> 4;
      int cq = fi & 15;
      *reinterpret_cast<f4*>(&Ws[k][cq * 4]) =
          *reinterpret_cast<const f4*>(&W[(size_t)(k0 + k) * DD + c0 + cq * 4]);
    }
    __syncthreads();
#pragma unroll
    for (int k = 0; k < 32; ++k) {
      f4 xv = *reinterpret_cast<const f4*>(&Xs[k][ty * 4]);
      f4 wv = *reinterpret_cast<const f4*>(&Ws[k][tx * 4]);
      float xs[4] = {xv.x, xv.y, xv.z, xv.w};
      float ws[4] = {wv.x, wv.y, wv.z, wv.w};
#pragma unroll
      for (int i = 0; i < 4; ++i)
#pragma unroll
        for (int j = 0; j < 4; ++j) acc[i][j] += xs[i] * ws[j];
    }
    __syncthreads();
  }
#pragma unroll
  for (int i = 0; i < 4; ++i) {
    f4 v = {acc[i][0], acc[i][1], acc[i][2], acc[i][3]};
    *reinterpret_cast<f4*>(&H[(size_t)(r0 + ty * 4 + i) * DD + c0 + tx * 4]) = v;
  }

  if (c0 == 0) {
    // s,t for rows r0..r0+63 via s = X@(W@a1), t = X@(W@a2)
    int wid = tid >> 6, lane = tid & 63;
    float* wv1 = &Xs[0][0];        // [512]
    float* wv2 = &Xs[0][0] + 512;  // [512]
    for (int k = tid; k < KDIM; k += 256) {
      float a1acc = 0.f, a2acc = 0.f;
#pragma unroll 8
      for (int d4 = 0; d4 < DD / 4; ++d4) {
        f4 wrow = *reinterpret_cast<const f4*>(&W[(size_t)k * DD + d4 * 4]);
        f4 a1v = *reinterpret_cast<const f4*>(&av[d4 * 4]);
        f4 a2v = *reinterpret_cast<const f4*>(&av[DD + d4 * 4]);
        a1acc += dot4(wrow, a1v);
        a2acc += dot4(wrow, a2v);
      }
      wv1[k] = a1acc;
      wv2[k] = a2acc;
    }
    __syncthreads();
    f4 w1a = *reinterpret_cast<const f4*>(&wv1[lane * 8]);
    f4 w1b = *reinterpret_cast<const f4*>(&wv1[lane * 8 + 4]);
    f4 w2a = *reinterpret_cast<const f4*>(&wv2[lane * 8]);
    f4 w2b = *reinterpret_cast<const f4*>(&wv2[lane * 8 + 4]);
    for (int rr = 0; rr < 16; ++rr) {
      int i = r0 + wid * 16 + rr;
      f4 xa = *reinterpret_cast<const f4*>(&X[(size_t)i * KDIM + lane * 8]);
      f4 xb = *reinterpret_cast<const f4*>(&X[(size_t)i * KDIM + lane * 8 + 4]);
      float p1 = dot4(xa, w1a) + dot4(xb, w1b);
      float p2 = dot4(xa, w2a) + dot4(xb, w2b);
      for (int off = 32; off > 0; off >>= 1) {
        p1 += __shfl_down(p1, off);
        p2 += __shfl_down(p2, off);
      }
      if (lane == 0) { s[i] = p1; t[i] = p2; }
    }
  }
}

// ---------- K2: bucket sort + per-bucket totals + E/c (one kernel) ----------
// Block c owns bucket c AND rows c*32..c*32+31.  Streams all of t; every block
// redundantly computes tmin/tmax/histogram (identical fp order -> bitwise
// consistent), so each block derives its own CSR offset without cross-block
// sync.  Members sorted by (value, index) -> tz/Ez/Hs are globally
// value-sorted; prefix sets match the rank-sort version exactly.
__global__ __launch_bounds__(256) void k_vtot(const float* __restrict__ s,
                                              const float* __restrict__ t,
                                              const float* __restrict__ H,
                                              float* __restrict__ E1,
                                              float* __restrict__ E2,
                                              float* __restrict__ c1,
                                              float* __restrict__ c2,
                                              float* __restrict__ Vtot1,
                                              float* __restrict__ Vtot2,
                                              float* __restrict__ Vcs1,
                                              float* __restrict__ Vcs2,
                                              float* __restrict__ tz,
                                              float* __restrict__ Ez1,
                                              float* __restrict__ Ez2,
                                              float* __restrict__ Hs,
                                              int* __restrict__ boffg,
                                              int* __restrict__ cntg,
                                              float* __restrict__ tmm) {
  __shared__ float ts[NN];        // 32 KB
  __shared__ int hist[NCB];
  __shared__ int sh1[NCB];        // inclusive scan of hist
  __shared__ int tcnt[256];       // per-thread-slice bucket-c matches
  __shared__ int sh2[256];        // inclusive scan of tcnt
  __shared__ int mlist[2048];     // bucket-c members, index order
  __shared__ int srt[2048];       // bucket-c members, (value,index) order
  __shared__ float lred[4], lredn[4];
  const int c = blockIdx.x, tid = threadIdx.x;
  const int wid = tid >> 6, lane = tid & 63;

  // load t -> LDS, min/max with fixed reduction order
  float mx = -1e30f, mn = 1e30f;
#pragma unroll
  for (int q = 0; q < 8; ++q) {
    int idx = (q * 256 + tid) * 4;
    f4 v = *reinterpret_cast<const f4*>(&t[idx]);
    *reinterpret_cast<f4*>(&ts[idx]) = v;
    mx = fmaxf(mx, fmaxf(fmaxf(v.x, v.y), fmaxf(v.z, v.w)));
    mn = fminf(mn, fminf(fminf(v.x, v.y), fminf(v.z, v.w)));
  }
  for (int off = 32; off > 0; off >>= 1) {
    mx = fmaxf(mx, __shfl_down(mx, off));
    mn = fminf(mn, __shfl_down(mn, off));
  }
  if (lane == 0) { lred[wid] = mx; lredn[wid] = mn; }
  __syncthreads();
  float tmax = fmaxf(fmaxf(lred[0], lred[1]), fmaxf(lred[2], lred[3]));
  float tmin = fminf(fminf(lredn[0], lredn[1]), fminf(lredn[2], lredn[3]));
  float range = tmax - tmin;
  float sc = (range > 0.f) ? (float)NCB / range : 0.f;
  if (c == 0 && tid == 0) { tmm[0] = tmin; tmm[1] = sc; }

  // own rows: E1/E2 and softmax coefficients c1/c2
  if (tid < 32) {
    int i = c * 32 + tid;
    float ti = ts[i];
    E1[i] = expf(ti);
    E2[i] = expf(0.2f * ti);
    float si = s[i];
    float e = si + tmax;
    float mm = e > 0.f ? e : 0.2f * e;
    c1[i] = expf(si - mm);
    c2[i] = expf(0.2f * si - mm);
  }

  // histogram + per-slice count of bucket-c members
  hist[tid] = 0;
  __syncthreads();
  int myc = 0;
  for (int k = 0; k < 32; ++k) {
    int j = tid * 32 + k;
    int b = bk(ts[j], tmin, sc);
    atomicAdd(&hist[b], 1);
    myc += (b == c);
  }
  tcnt[tid] = myc;
  __syncthreads();
  int h0 = hist[tid], tc0 = tcnt[tid];
  sh1[tid] = h0; sh2[tid] = tc0;
  __syncthreads();
  for (int off = 1; off < 256; off <<= 1) {
    int a1 = (tid >= off) ? sh1[tid - off] : 0;
    int a2 = (tid >= off) ? sh2[tid - off] : 0;
    __syncthreads();
    sh1[tid] += a1; sh2[tid] += a2;
    __syncthreads();
  }
  const int boffc = (c > 0) ? sh1[c - 1] : 0;
  const int nm = hist[c];
  const int tb = sh2[tid] - tc0;   // exclusive base for this thread's slice
  if (tid == 0) { boffg[c] = boffc; cntg[c] = nm; }

  // pass 2: member list in index order (deterministic)
  int w = 0;
  for (int k = 0; k < 32; ++k) {
    int j = tid * 32 + k;
    if (bk(ts[j], tmin, sc) == c) {
      int slot = tb + w;
      if (slot < 2048) mlist[slot] = j;
      ++w;
    }
  }
  __syncthreads();

  // in-bucket rank by (value, index) -> globally value-sorted order
  for (int k = tid; k < nm; k += 256) {
    int j = mlist[k];
    float v = ts[j];
    int r = 0;
    for (int k2 = 0; k2 < nm; ++k2) {
      int j2 = mlist[k2];
      float v2 = ts[j2];
      r += (v2 < v) || (v2 == v && j2 < j);
    }
    srt[r] = j;
  }
  __syncthreads();

  // gather sorted Hs/tz/Ez + accumulate bucket totals
  float a1 = 0.f, a2 = 0.f, scs1 = 0.f, scs2 = 0.f;
  for (int r2 = 0; r2 < nm; ++r2) {
    int j = srt[r2];
    float tv = ts[j];
    float e1 = expf(tv), e2 = expf(0.2f * tv);
    float hv = H[(size_t)j * DD + tid];
    Hs[(size_t)(boffc + r2) * DD + tid] = hv;
    a1 += e1 * hv;
    a2 += e2 * hv;
    if (tid == 0) {
      tz[boffc + r2] = tv;
      Ez1[boffc + r2] = e1;
      Ez2[boffc + r2] = e2;
      scs1 += e1;
      scs2 += e2;
    }
  }
  Vtot1[c * DD + tid] = a1;
  Vtot2[c * DD + tid] = a2;
  if (tid == 0) { Vcs1[c] = scs1; Vcs2[c] = scs2; }
}

// ---------- K3: Vpre (triangular, pipelined) + scalar scan + f1/f2 ----------
__global__ __launch_bounds__(256) void k_scan(const float* __restrict__ Vtot1,
                                              const float* __restrict__ Vtot2,
                                              const float* __restrict__ Vcs1,
                                              const float* __restrict__ Vcs2,
                                              const float* __restrict__ tz,
                                              const float* __restrict__ Ez1,
                                              const float* __restrict__ Ez2,
                                              const int* __restrict__ boffg,
                                              const int* __restrict__ cntg,
                                              const float* __restrict__ tmm,
                                              const float* __restrict__ s,
                                              const float* __restrict__ c1,
                                              const float* __restrict__ c2,
                                              float* __restrict__ Vpre1,
                                              float* __restrict__ Vpre2,
                                              float* __restrict__ f1,
                                              float* __restrict__ f2) {
  __shared__ float sc1[NCB], sc2[NCB];
  const int c = blockIdx.x;
  const int d = threadIdx.x;
  float r1a = 0.f, r1b = 0.f, r2a = 0.f, r2b = 0.f;
  int cc = 0;
  for (; cc + 4 <= c; cc += 4) {
    r1a += Vtot1[(cc + 0) * DD + d];
    r1b += Vtot1[(cc + 1) * DD + d];
    r1a += Vtot1[(cc + 2) * DD + d];
    r1b += Vtot1[(cc + 3) * DD + d];
    r2a += Vtot2[(cc + 0) * DD + d];
    r2b += Vtot2[(cc + 1) * DD + d];
    r2a += Vtot2[(cc + 2) * DD + d];
    r2b += Vtot2[(cc + 3) * DD + d];
  }
  for (; cc < c; ++cc) {
    r1a += Vtot1[cc * DD + d];
    r2a += Vtot2[cc * DD + d];
  }
  float r1 = r1a + r1b, r2 = r2a + r2b;
  Vpre1[(size_t)c * DD + d] = r1;
  Vpre2[(size_t)c * DD + d] = r2;
  if (c == NCB - 1) {
    Vpre1[(size_t)NCB * DD + d] = r1 + Vtot1[c * DD + d];
    Vpre2[(size_t)NCB * DD + d] = r2 + Vtot2[c * DD + d];
  }
  sc1[d] = Vcs1[d];
  sc2[d] = Vcs2[d];
  __syncthreads();
  for (int off = 1; off < NCB; off <<= 1) {
    float y1 = (d >= off) ? sc1[d - off] : 0.f;
    float y2 = (d >= off) ? sc2[d - off] : 0.f;
    __syncthreads();
    sc1[d] += y1; sc2[d] += y2;
    __syncthreads();
  }
  if (d < 32) {
    int i = c * 32 + d;
    float th = -s[i];
    float tmin = tmm[0], scl = tmm[1];
    int b = bk(th, tmin, scl);
    float sp1 = b ? sc1[b - 1] : 0.f;
    float sp2 = b ? sc2[b - 1] : 0.f;
    int base = boffg[b], n = cntg[b];
    for (int k = 0; k < n; ++k) {     // sorted -> early break
      float tv = tz[base + k];
      if (tv > th) break;
      sp1 += Ez1[base + k];
      sp2 += Ez2[base + k];
    }
    float T1s = sc1[NCB - 1];
    float a1 = c1[i], a2 = c2[i];
    float Z = a1 * (T1s - sp1) + a2 * sp2;
    float rZ = 1.0f / Z;
    f1[i] = rZ * a1;
    f2[i] = rZ * a2;
  }
}

// ---------- K4: merged finalize (4 rows) + A-stream tile (2048 blocks) -------
__global__ __launch_bounds__(256) void k_finstream(const float* __restrict__ s,
                                                   const float* __restrict__ t,
                                                   const float* __restrict__ E1,
                                                   const float* __restrict__ E2,
                                                   const float* __restrict__ f1,
                                                   const float* __restrict__ f2,
                                                   const float* __restrict__ tz,
                                                   const float* __restrict__ Ez1,
                                                   const float* __restrict__ Ez2,
                                                   const float* __restrict__ Hs,
                                                   const float* __restrict__ Vpre1,
                                                   const float* __restrict__ Vpre2,
                                                   const int* __restrict__ boffg,
                                                   const int* __restrict__ cntg,
                                                   const float* __restrict__ tmm,
                                                   float* __restrict__ out,
                                                   float* __restrict__ A) {
  const int bb = blockIdx.x;
  const int d = threadIdx.x;
  // ---- finalize rows bb*4..bb*4+3 ----
  {
    float tmin = tmm[0], scl = tmm[1];
    float T1 = Vpre1[(size_t)NCB * DD + d];
#pragma unroll
    for (int r = 0; r < 4; ++r) {
      int i = bb * 4 + r;
      float th = -s[i];
      int b = bk(th, tmin, scl);
      int base = boffg[b], n = cntg[b];
      float P1 = Vpre1[(size_t)b * DD + d];
      float P2 = Vpre2[(size_t)b * DD + d];
      for (int k = 0; k < n; ++k) {   // sorted -> early break
        float tv = tz[base + k];
        if (tv > th) break;
        float hv = Hs[(size_t)(base + k) * DD + d];
        P1 += Ez1[base + k] * hv;
        P2 += Ez2[base + k] * hv;
      }
      out[(size_t)i * DD + d] = f1[i] * (T1 - P1) + f2[i] * P2;
    }
  }
  // ---- A-stream tile: rows (bb>>3)*32.., cols (bb&7)*1024.. ----
  {
    int i0 = (bb >> 3) * 32;
    int j0 = (bb & 7) * 1024 + d * 4;
    f4 t4  = *reinterpret_cast<const f4*>(&t[j0]);
    f4 e14 = *reinterpret_cast<const f4*>(&E1[j0]);
    f4 e24 = *reinterpret_cast<const f4*>(&E2[j0]);
#pragma unroll 4
    for (int rr = 0; rr < 32; ++rr) {
      int i = i0 + rr;
      float ss = s[i], ff1 = f1[i], ff2 = f2[i];
      f4v o;
      float e;
      e = ss + t4.x; o.x = (e > 0.f) ? ff1 * e14.x : ff2 * e24.x;
      e = ss + t4.y; o.y = (e > 0.f) ? ff1 * e14.y : ff2 * e24.y;
      e = ss + t4.z; o.z = (e > 0.f) ? ff1 * e14.z : ff2 * e24.z;
      e = ss + t4.w; o.w = (e > 0.f) ? ff1 * e14.w : ff2 * e24.w;
      __builtin_nontemporal_store(o, reinterpret_cast<f4v*>(&A[(size_t)i * NN + j0]));
    }
  }
}

extern "C" void kernel_launch(void* const* d_in, const int* in_sizes, int n_in,
                              void* d_out, int out_size, void* d_ws, size_t ws_size,
                              hipStream_t stream) {
  const float* X  = (const float*)d_in[0];
  const float* W  = (const float*)d_in[1];
  const float* av = (const float*)d_in[2];
  float* outp = (float*)d_out;                  // [NN*DD]
  float* A = outp + (size_t)NN * DD;            // [NN*NN]
  float* wsp = (float*)d_ws;

  // ws layout (floats); total 2,457,600 floats = 9.83 MB (ws >= 9.96 MB proven R11)
  float* s     = wsp + 0;
  float* t     = wsp + 8192;
  float* E1    = wsp + 16384;
  float* E2    = wsp + 24576;
  float* c1    = wsp + 32768;
  float* c2    = wsp + 40960;
  float* f1    = wsp + 49152;
  float* f2    = wsp + 57344;
  float* Vtot1 = wsp + 65536;     // 65536
  float* Vtot2 = wsp + 131072;    // 65536
  float* Vpre1 = wsp + 196608;    // 65792 (257*256)
  float* Vpre2 = wsp + 262400;    // 65792
  float* Vcs1  = wsp + 328192;    // 256
  float* Vcs2  = wsp + 328448;    // 256
  float* tz    = wsp + 328704;    // 8192
  float* Ez1   = wsp + 336896;    // 8192
  float* Ez2   = wsp + 345088;    // 8192
  int*   boffg = (int*)(wsp + 353280);  // 256
  int*   cntg  = (int*)(wsp + 353536);  // 256
  float* tmm   = wsp + 353792;    // 2
  float* Hs    = wsp + 360448;    // 2097152 (value-sorted H)

  // H lives in the A-region (read only by k_vtot, long before A is written)
  float* H = A;

  k_gemm<<<dim3(NN / 64, DD / 64), 256, 0, stream>>>(X, W, av, H, s, t);
  k_vtot<<<NCB, 256, 0, stream>>>(s, t, H, E1, E2, c1, c2, Vtot1, Vtot2,
                                  Vcs1, Vcs2, tz, Ez1, Ez2, Hs, boffg, cntg, tmm);
  k_scan<<<NCB, 256, 0, stream>>>(Vtot1, Vtot2, Vcs1, Vcs2, tz, Ez1, Ez2,
                                  boffg, cntg, tmm, s, c1, c2,
                                  Vpre1, Vpre2, f1, f2);
  k_finstream<<<NN / 4, 256, 0, stream>>>(s, t, E1, E2, f1, f2, tz, Ez1, Ez2,
                                          Hs, Vpre1, Vpre2, boffg, cntg, tmm,
                                          outp, A);
}

// Round 13
// 202.649 us; speedup vs baseline: 1.3223x; 1.3223x over previous
//
#include <hip/hip_runtime.h>
#include <math.h>

#define NN 8192
#define KDIM 512
#define DD 256
#define CS 32      // prefix chunk size
#define NC 256     // number of chunks

typedef float4 f4;
typedef __attribute__((ext_vector_type(4))) float f4v;  // native vec for nontemporal

__device__ __forceinline__ float dot4(const f4& x, const f4& y) {
  return x.x * y.x + x.y * y.y + x.z * y.z + x.w * y.w;
}

// ---------- K1: H = X @ W (64x64 tile) + s,t tail + scratch zeroing ----------
__global__ __launch_bounds__(256) void k_gemm(const float* __restrict__ X,
                                              const float* __restrict__ W,
                                              const float* __restrict__ av,
                                              float* __restrict__ H,
                                              float* __restrict__ s,
                                              float* __restrict__ t,
                                              float* __restrict__ Ctot1,
                                              float* __restrict__ cs1) {
  __shared__ float Xs[32][64];  // [k][r] (transposed); reused as wv1/wv2 after
  __shared__ float Ws[32][64];  // [k][c]
  const int tid = threadIdx.x;
  const int tx = tid & 15;
  const int ty = tid >> 4;
  const int r0 = blockIdx.x * 64;
  const int c0 = blockIdx.y * 64;

  // by==1 blocks zero Ctot1||Ctot2 (contiguous 131072 floats);
  // by==2, bx==0 zeroes cs1||cs2 (contiguous 512 floats).
  if (blockIdx.y == 1) {
    f4 z = {0.f, 0.f, 0.f, 0.f};
    *reinterpret_cast<f4*>(&Ctot1[blockIdx.x * 1024 + tid * 4]) = z;
  } else if (blockIdx.y == 2 && blockIdx.x == 0 && tid < 128) {
    f4 z = {0.f, 0.f, 0.f, 0.f};
    *reinterpret_cast<f4*>(&cs1[tid * 4]) = z;
  }

  float acc[4][4] = {};
  for (int k0 = 0; k0 < KDIM; k0 += 32) {
#pragma unroll
    for (int q = 0; q < 2; ++q) {
      int fi = tid + q * 256;
      int r = fi >> 3;
      int kq = fi & 7;
      f4 v = *reinterpret_cast<const f4*>(&X[(size_t)(r0 + r) * KDIM + k0 + kq * 4]);
      Xs[kq * 4 + 0][r] = v.x; Xs[kq * 4 + 1][r] = v.y;
      Xs[kq * 4 + 2][r] = v.z; Xs[kq * 4 + 3][r] = v.w;
    }
#pragma unroll
    for (int q = 0; q < 2; ++q) {
      int fi = tid + q * 256;
      int k = fi >> 4;
      int cq = fi & 15;
      *reinterpret_cast<f4*>(&Ws[k][cq * 4]) =
          *reinterpret_cast<const f4*>(&W[(size_t)(k0 + k) * DD + c0 + cq * 4]);
    }
    __syncthreads();
#pragma unroll
    for (int k = 0; k < 32; ++k) {
      f4 xv = *reinterpret_cast<const f4*>(&Xs[k][ty * 4]);
      f4 wv = *reinterpret_cast<const f4*>(&Ws[k][tx * 4]);
      float xs[4] = {xv.x, xv.y, xv.z, xv.w};
      float ws[4] = {wv.x, wv.y, wv.z, wv.w};
#pragma unroll
      for (int i = 0; i < 4; ++i)
#pragma unroll
        for (int j = 0; j < 4; ++j) acc[i][j] += xs[i] * ws[j];
    }
    __syncthreads();
  }
#pragma unroll
  for (int i = 0; i < 4; ++i) {
    f4 v = {acc[i][0], acc[i][1], acc[i][2], acc[i][3]};
    *reinterpret_cast<f4*>(&H[(size_t)(r0 + ty * 4 + i) * DD + c0 + tx * 4]) = v;
  }

  if (c0 == 0) {
    // s,t for rows r0..r0+63 via s = X@(W@a1), t = X@(W@a2)
    int wid = tid >> 6, lane = tid & 63;
    float* wv1 = &Xs[0][0];        // [512]
    float* wv2 = &Xs[0][0] + 512;  // [512]
    for (int k = tid; k < KDIM; k += 256) {
      float a1acc = 0.f, a2acc = 0.f;
#pragma unroll 8
      for (int d4 = 0; d4 < DD / 4; ++d4) {
        f4 wrow = *reinterpret_cast<const f4*>(&W[(size_t)k * DD + d4 * 4]);
        f4 a1v = *reinterpret_cast<const f4*>(&av[d4 * 4]);
        f4 a2v = *reinterpret_cast<const f4*>(&av[DD + d4 * 4]);
        a1acc += dot4(wrow, a1v);
        a2acc += dot4(wrow, a2v);
      }
      wv1[k] = a1acc;
      wv2[k] = a2acc;
    }
    __syncthreads();
    f4 w1a = *reinterpret_cast<const f4*>(&wv1[lane * 8]);
    f4 w1b = *reinterpret_cast<const f4*>(&wv1[lane * 8 + 4]);
    f4 w2a = *reinterpret_cast<const f4*>(&wv2[lane * 8]);
    f4 w2b = *reinterpret_cast<const f4*>(&wv2[lane * 8 + 4]);
    for (int rr = 0; rr < 16; ++rr) {
      int i = r0 + wid * 16 + rr;
      f4 xa = *reinterpret_cast<const f4*>(&X[(size_t)i * KDIM + lane * 8]);
      f4 xb = *reinterpret_cast<const f4*>(&X[(size_t)i * KDIM + lane * 8 + 4]);
      float p1 = dot4(xa, w1a) + dot4(xb, w1b);
      float p2 = dot4(xa, w2a) + dot4(xb, w2b);
      for (int off = 32; off > 0; off >>= 1) {
        p1 += __shfl_down(p1, off);
        p2 += __shfl_down(p2, off);
      }
      if (lane == 0) { s[i] = p1; t[i] = p2; }
    }
  }
}

// ---------- K2: tmax, E/c, rank+ki for 16 keys, AND chunk totals (atomics) ----
__global__ __launch_bounds__(256) void k_mid(const float* __restrict__ s,
                                             const float* __restrict__ t,
                                             const float* __restrict__ H,
                                             float* __restrict__ E1,
                                             float* __restrict__ E2,
                                             float* __restrict__ c1,
                                             float* __restrict__ c2,
                                             int* __restrict__ perm,
                                             float* __restrict__ Es1,
                                             float* __restrict__ Es2,
                                             int* __restrict__ kidx,
                                             float* __restrict__ Ctot1,
                                             float* __restrict__ Ctot2,
                                             float* __restrict__ cs1,
                                             float* __restrict__ cs2) {
  __shared__ float lred[4];
  __shared__ int   kJ[16], kC[16];
  __shared__ float kE1[16], kE2[16];
  const int b = blockIdx.x, tid = threadIdx.x;
  const int wid = tid >> 6, lane = tid & 63;
  float m = -1e30f;
#pragma unroll
  for (int q = 0; q < 8; ++q) {
    int idx = (q * 256 + tid) * 4;
    f4 v = *reinterpret_cast<const f4*>(&t[idx]);
    m = fmaxf(m, fmaxf(fmaxf(v.x, v.y), fmaxf(v.z, v.w)));
  }
  for (int off = 32; off > 0; off >>= 1) m = fmaxf(m, __shfl_down(m, off));
  if (lane == 0) lred[wid] = m;
  __syncthreads();
  float tmax = fmaxf(fmaxf(lred[0], lred[1]), fmaxf(lred[2], lred[3]));

  if (tid < 16) {
    int i = b * 16 + tid;
    float ti = t[i];
    E1[i] = expf(ti);
    E2[i] = expf(0.2f * ti);
    float si = s[i];
    float e = si + tmax;
    float mm = e > 0.f ? e : 0.2f * e;
    c1[i] = expf(si - mm);
    c2[i] = expf(0.2f * si - mm);
  }

  // 4 rank keys + 4 s-keys per wave (wave-uniform keys, per-lane value slices)
  float tkv[4], skv[4]; int jj[4], cnt[4], cntk[4];
#pragma unroll
  for (int q = 0; q < 4; ++q) {
    jj[q] = b * 16 + wid * 4 + q;
    tkv[q] = t[jj[q]];
    skv[q] = -s[jj[q]];
    cnt[q] = 0;
    cntk[q] = 0;
  }
  for (int m2 = 0; m2 < 32; ++m2) {
    int i4 = m2 * 64 + lane;
    f4 v = *reinterpret_cast<const f4*>(&t[i4 * 4]);
    int base = i4 * 4;
#pragma unroll
    for (int q = 0; q < 4; ++q) {
      cnt[q] += (v.x < tkv[q]) || (v.x == tkv[q] && base + 0 < jj[q]);
      cnt[q] += (v.y < tkv[q]) || (v.y == tkv[q] && base + 1 < jj[q]);
      cnt[q] += (v.z < tkv[q]) || (v.z == tkv[q] && base + 2 < jj[q]);
      cnt[q] += (v.w < tkv[q]) || (v.w == tkv[q] && base + 3 < jj[q]);
      cntk[q] += (v.x <= skv[q]) + (v.y <= skv[q]) + (v.z <= skv[q]) + (v.w <= skv[q]);
    }
  }
#pragma unroll
  for (int q = 0; q < 4; ++q) {
    int c = cnt[q], ck = cntk[q];
    for (int off = 32; off > 0; off >>= 1) {
      c += __shfl_down(c, off);
      ck += __shfl_down(ck, off);
    }
    if (lane == 0) {
      float e1 = expf(tkv[q]);        // bitwise == E1[jj[q]]
      float e2 = expf(0.2f * tkv[q]);
      perm[c] = jj[q];
      Es1[c] = e1;
      Es2[c] = e2;
      kidx[jj[q]] = ck;
      int cc = c >> 5;
      int idx = wid * 4 + q;
      kJ[idx] = jj[q]; kC[idx] = cc; kE1[idx] = e1; kE2[idx] = e2;
      atomicAdd(&cs1[cc], e1);
      atomicAdd(&cs2[cc], e2);
    }
  }
  __syncthreads();
  // chunk-total accumulation: 16 keys x 256 cols, fire-and-forget atomics
#pragma unroll
  for (int q = 0; q < 16; ++q) {
    int j = kJ[q], cc = kC[q];
    float h = H[(size_t)j * DD + tid];
    atomicAdd(&Ctot1[cc * DD + tid], kE1[q] * h);
    atomicAdd(&Ctot2[cc * DD + tid], kE2[q] * h);
  }
}

// ---------- K3: Cpre (triangular, pipelined) + scalar scan + f1/f2 ----------
__global__ __launch_bounds__(256) void k_scan(const float* __restrict__ Ctot1,
                                              const float* __restrict__ Ctot2,
                                              const float* __restrict__ cs1,
                                              const float* __restrict__ cs2,
                                              const float* __restrict__ Es1,
                                              const float* __restrict__ Es2,
                                              const int* __restrict__ kidx,
                                              const float* __restrict__ c1,
                                              const float* __restrict__ c2,
                                              float* __restrict__ Cpre1,
                                              float* __restrict__ Cpre2,
                                              float* __restrict__ f1,
                                              float* __restrict__ f2) {
  __shared__ float sc1[NC], sc2[NC];
  const int c = blockIdx.x;
  const int d = threadIdx.x;
  float r1a = 0.f, r1b = 0.f, r2a = 0.f, r2b = 0.f;
  int cc = 0;
  for (; cc + 4 <= c; cc += 4) {
    r1a += Ctot1[(cc + 0) * DD + d];
    r1b += Ctot1[(cc + 1) * DD + d];
    r1a += Ctot1[(cc + 2) * DD + d];
    r1b += Ctot1[(cc + 3) * DD + d];
    r2a += Ctot2[(cc + 0) * DD + d];
    r2b += Ctot2[(cc + 1) * DD + d];
    r2a += Ctot2[(cc + 2) * DD + d];
    r2b += Ctot2[(cc + 3) * DD + d];
  }
  for (; cc < c; ++cc) {
    r1a += Ctot1[cc * DD + d];
    r2a += Ctot2[cc * DD + d];
  }
  float r1 = r1a + r1b, r2 = r2a + r2b;
  Cpre1[(size_t)c * DD + d] = r1;
  Cpre2[(size_t)c * DD + d] = r2;
  if (c == NC - 1) {
    Cpre1[(size_t)NC * DD + d] = r1 + Ctot1[c * DD + d];
    Cpre2[(size_t)NC * DD + d] = r2 + Ctot2[c * DD + d];
  }
  sc1[d] = cs1[d];
  sc2[d] = cs2[d];
  __syncthreads();
  for (int off = 1; off < NC; off <<= 1) {
    float y1 = (d >= off) ? sc1[d - off] : 0.f;
    float y2 = (d >= off) ? sc2[d - off] : 0.f;
    __syncthreads();
    sc1[d] += y1; sc2[d] += y2;
    __syncthreads();
  }
  if (d < 32) {
    int i = c * 32 + d;
    int ki = kidx[i];
    int ci = ki >> 5;
    float sp1 = ci ? sc1[ci - 1] : 0.f;
    float sp2 = ci ? sc2[ci - 1] : 0.f;
    for (int m = ci * CS; m < ki; ++m) { sp1 += Es1[m]; sp2 += Es2[m]; }
    float T1s = sc1[NC - 1];
    float a1 = c1[i], a2 = c2[i];
    float Z = a1 * (T1s - sp1) + a2 * sp2;
    float rZ = 1.0f / Z;
    f1[i] = rZ * a1;
    f2[i] = rZ * a2;
  }
}

// ---------- K4: merged finalize (4 rows) + A-stream tile (2048 blocks) -------
__global__ __launch_bounds__(256) void k_finstream(const int* __restrict__ kidx,
                                                   const float* __restrict__ Es1,
                                                   const float* __restrict__ Es2,
                                                   const int* __restrict__ perm,
                                                   const float* __restrict__ H,
                                                   const float* __restrict__ Cpre1,
                                                   const float* __restrict__ Cpre2,
                                                   const float* __restrict__ f1,
                                                   const float* __restrict__ f2,
                                                   float* __restrict__ out,
                                                   const float* __restrict__ s,
                                                   const float* __restrict__ t,
                                                   const float* __restrict__ E1,
                                                   const float* __restrict__ E2,
                                                   float* __restrict__ A) {
  const int bb = blockIdx.x;
  const int d = threadIdx.x;
  // ---- finalize rows bb*4..bb*4+3 ----
  {
    float T1 = Cpre1[(size_t)NC * DD + d];
#pragma unroll
    for (int r = 0; r < 4; ++r) {
      int i = bb * 4 + r;
      int ki = kidx[i];
      int ci = ki >> 5;
      float P1 = Cpre1[(size_t)ci * DD + d];
      float P2 = Cpre2[(size_t)ci * DD + d];
      for (int m = ci * CS; m < ki; ++m) {
        float h = H[(size_t)perm[m] * DD + d];
        P1 += Es1[m] * h;
        P2 += Es2[m] * h;
      }
      out[(size_t)i * DD + d] = f1[i] * (T1 - P1) + f2[i] * P2;
    }
  }
  // ---- A-stream tile: rows (bb>>3)*32.., cols (bb&7)*1024.. ----
  {
    int i0 = (bb >> 3) * 32;
    int j0 = (bb & 7) * 1024 + d * 4;
    f4 t4  = *reinterpret_cast<const f4*>(&t[j0]);
    f4 e14 = *reinterpret_cast<const f4*>(&E1[j0]);
    f4 e24 = *reinterpret_cast<const f4*>(&E2[j0]);
#pragma unroll 4
    for (int rr = 0; rr < 32; ++rr) {
      int i = i0 + rr;
      float ss = s[i], ff1 = f1[i], ff2 = f2[i];
      f4v o;
      float e;
      e = ss + t4.x; o.x = (e > 0.f) ? ff1 * e14.x : ff2 * e24.x;
      e = ss + t4.y; o.y = (e > 0.f) ? ff1 * e14.y : ff2 * e24.y;
      e = ss + t4.z; o.z = (e > 0.f) ? ff1 * e14.z : ff2 * e24.z;
      e = ss + t4.w; o.w = (e > 0.f) ? ff1 * e14.w : ff2 * e24.w;
      __builtin_nontemporal_store(o, reinterpret_cast<f4v*>(&A[(size_t)i * NN + j0]));
    }
  }
}

extern "C" void kernel_launch(void* const* d_in, const int* in_sizes, int n_in,
                              void* d_out, int out_size, void* d_ws, size_t ws_size,
                              hipStream_t stream) {
  const float* X  = (const float*)d_in[0];
  const float* W  = (const float*)d_in[1];
  const float* av = (const float*)d_in[2];
  float* outp = (float*)d_out;                  // [NN*DD]
  float* A = outp + (size_t)NN * DD;            // [NN*NN]
  float* wsp = (float*)d_ws;

  // ws layout (floats); total 2,490,368 floats = 9.96 MB (proven fit in R11)
  float* s     = wsp + 0;
  float* t     = wsp + 8192;
  float* E1    = wsp + 16384;
  float* E2    = wsp + 24576;
  float* c1    = wsp + 32768;
  float* c2    = wsp + 40960;
  float* f1    = wsp + 49152;
  float* f2    = wsp + 57344;
  float* Ctot1 = wsp + 65536;     // 65536 (contiguous with Ctot2 for zeroing)
  float* Ctot2 = wsp + 131072;    // 65536
  float* Cpre1 = wsp + 196608;    // 65792 (257*256)
  float* Cpre2 = wsp + 262400;    // 65792
  float* cs1   = wsp + 328192;    // 256 (contiguous with cs2 for zeroing)
  float* cs2   = wsp + 328448;    // 256
  float* Es1   = wsp + 328704;    // 8192
  float* Es2   = wsp + 336896;    // 8192
  int*   kidx  = (int*)(wsp + 345088);  // 8192
  int*   perm  = (int*)(wsp + 353280);  // 8192
  float* H     = wsp + 393216;    // 2097152

  k_gemm<<<dim3(NN / 64, DD / 64), 256, 0, stream>>>(X, W, av, H, s, t, Ctot1, cs1);
  k_mid<<<NN / 16, 256, 0, stream>>>(s, t, H, E1, E2, c1, c2, perm, Es1, Es2,
                                     kidx, Ctot1, Ctot2, cs1, cs2);
  k_scan<<<NC, 256, 0, stream>>>(Ctot1, Ctot2, cs1, cs2, Es1, Es2, kidx, c1, c2,
                                 Cpre1, Cpre2, f1, f2);
  k_finstream<<<NN / 4, 256, 0, stream>>>(kidx, Es1, Es2, perm, H, Cpre1, Cpre2,
                                          f1, f2, outp, s, t, E1, E2, A);
}